// Round 1
// baseline (759.037 us; speedup 1.0000x reference)
//
#include <hip/hip_runtime.h>

#define NNODES 65536
#define NEDGES 1048576
#define HDIM 128
#define NCLS 40

// ---------------- Wdyn = relu(w0[f]*E_meta[g,h] + b0[f,h]) ----------------
__global__ __launch_bounds__(256) void wdyn_kernel(
    const float* __restrict__ w0, const float* __restrict__ em,
    const float* __restrict__ b0, float* __restrict__ W)
{
    int i = blockIdx.x * 256 + threadIdx.x;   // G*F*H = 524288
    int h = i & 127;
    int f = (i >> 7) & 127;
    int g = i >> 14;
    float v = w0[f] * em[g * 128 + h] + b0[f * 128 + h];
    W[i] = fmaxf(v, 0.0f);
}

// ---------------- degree histogram ----------------
__global__ __launch_bounds__(256) void hist_kernel(
    const int* __restrict__ dst, int* __restrict__ cnt, int nE)
{
    int e = blockIdx.x * 256 + threadIdx.x;
    if (e < nE) atomicAdd(&cnt[dst[e]], 1);
}

// ---------------- single-block scan: row_ptr / cursor / dis ----------------
__global__ __launch_bounds__(1024) void scan_kernel(
    const int* __restrict__ cnt, int* __restrict__ row_ptr,
    int* __restrict__ cursor, float* __restrict__ dis)
{
    __shared__ int ssum[1024];
    int t = threadIdx.x;
    int base = t * 64;
    int s = 0;
    for (int i = 0; i < 64; i++) s += cnt[base + i];
    ssum[t] = s;
    __syncthreads();
    int mine = s;
    for (int off = 1; off < 1024; off <<= 1) {
        int v = (t >= off) ? ssum[t - off] : 0;
        __syncthreads();
        ssum[t] += v;
        __syncthreads();
    }
    int run = ssum[t] - mine;  // exclusive prefix
    for (int i = 0; i < 64; i++) {
        int idx = base + i;
        int c = cnt[idx];
        row_ptr[idx] = run;
        cursor[idx] = run;
        dis[idx] = rsqrtf((float)(c + 1));   // +1 self loop; deg >= 1 always
        run += c;
    }
    if (t == 1023) row_ptr[NNODES] = run;
}

// ---------------- scatter edges into CSR (by dst) ----------------
__global__ __launch_bounds__(256) void scatter_kernel(
    const int* __restrict__ src, const int* __restrict__ dst,
    int* __restrict__ cursor, int* __restrict__ csr, int nE)
{
    int e = blockIdx.x * 256 + threadIdx.x;
    if (e < nE) {
        int pos = atomicAdd(&cursor[dst[e]], 1);
        csr[pos] = src[e];
    }
}

// ---------------- 128x128-tile SGEMM: C[n,:] = A[n,:] @ B (K=128, Ncols=128)
// perGroup: B indexed by node group (row>>11). dis!=null: scale row by dis[n].
__global__ __launch_bounds__(256) void gemm128(
    const float* __restrict__ A, const float* __restrict__ B,
    float* __restrict__ C, const float* __restrict__ dis, int perGroup)
{
    __shared__ float As[8][128];
    __shared__ float Bs[8][128];
    const int t = threadIdx.x;
    const int rowBase = blockIdx.x * 128;
    const float* Bp = perGroup ? (B + ((size_t)(rowBase >> 11) << 14)) : B;
    const int colg = (t & 15) << 3;   // 16 col groups * 8 cols
    const int rowg = (t >> 4) << 3;   // 16 row groups * 8 rows
    float acc[8][8];
#pragma unroll
    for (int i = 0; i < 8; i++)
#pragma unroll
        for (int j = 0; j < 8; j++) acc[i][j] = 0.0f;

    const int lr  = t >> 1;           // 0..127 row for A load
    const int kq  = (t & 1) << 2;     // 0 or 4
    const int kb  = t >> 5;           // 0..7 k-row for B load
    const int col4 = (t & 31) << 2;   // B col

    for (int k0 = 0; k0 < 128; k0 += 8) {
        float4 av = *(const float4*)(A + (size_t)(rowBase + lr) * 128 + k0 + kq);
        float4 bv = *(const float4*)(Bp + (size_t)(k0 + kb) * 128 + col4);
        As[kq + 0][lr] = av.x;
        As[kq + 1][lr] = av.y;
        As[kq + 2][lr] = av.z;
        As[kq + 3][lr] = av.w;
        *(float4*)&Bs[kb][col4] = bv;
        __syncthreads();
#pragma unroll
        for (int kk = 0; kk < 8; kk++) {
            float4 a0 = *(float4*)&As[kk][rowg];
            float4 a1 = *(float4*)&As[kk][rowg + 4];
            float4 b0 = *(float4*)&Bs[kk][colg];
            float4 b1 = *(float4*)&Bs[kk][colg + 4];
            float ar[8] = {a0.x, a0.y, a0.z, a0.w, a1.x, a1.y, a1.z, a1.w};
            float br[8] = {b0.x, b0.y, b0.z, b0.w, b1.x, b1.y, b1.z, b1.w};
#pragma unroll
            for (int i = 0; i < 8; i++)
#pragma unroll
                for (int j = 0; j < 8; j++)
                    acc[i][j] = fmaf(ar[i], br[j], acc[i][j]);
        }
        __syncthreads();
    }
#pragma unroll
    for (int i = 0; i < 8; i++) {
        int r = rowBase + rowg + i;
        float scale = dis ? dis[r] : 1.0f;
        float4 o0 = make_float4(acc[i][0] * scale, acc[i][1] * scale,
                                acc[i][2] * scale, acc[i][3] * scale);
        float4 o1 = make_float4(acc[i][4] * scale, acc[i][5] * scale,
                                acc[i][6] * scale, acc[i][7] * scale);
        *(float4*)(C + (size_t)r * 128 + colg) = o0;
        *(float4*)(C + (size_t)r * 128 + colg + 4) = o1;
    }
}

// ---------------- aggregation: out[n] = relu(dis[n]*(sum_src hws[src] + hws[n]) + b)
// hws is already scaled by dis[src] (fused in GEMM epilogue). One wave per node.
__global__ __launch_bounds__(256) void aggregate_kernel(
    const float* __restrict__ hws, const int* __restrict__ row_ptr,
    const int* __restrict__ csr, const float* __restrict__ dis,
    const float* __restrict__ bias, float* __restrict__ outh)
{
    int gid = blockIdx.x * 256 + threadIdx.x;
    int n = gid >> 6;
    int lane = gid & 63;
    const size_t fo = (size_t)(lane * 2);
    int beg = row_ptr[n], end = row_ptr[n + 1];
    float2 acc = *(const float2*)(hws + (size_t)n * 128 + fo);  // self (scaled)
    for (int i = beg; i < end; ++i) {
        int s = csr[i];
        float2 v = *(const float2*)(hws + (size_t)s * 128 + fo);
        acc.x += v.x;
        acc.y += v.y;
    }
    float d = dis[n];
    float2 b = *(const float2*)(bias + fo);
    float2 o;
    o.x = fmaxf(fmaf(d, acc.x, b.x), 0.0f);
    o.y = fmaxf(fmaf(d, acc.y, b.y), 0.0f);
    *(float2*)(outh + (size_t)n * 128 + fo) = o;
}

// ---------------- fused logits (K=128 -> 40) + log_softmax ----------------
// Block 256 = 4 waves; 8 nodes/wave (8 lanes/node, 5 cols/lane).
__global__ __launch_bounds__(256) void logits_lsm_kernel(
    const float* __restrict__ h, const float* __restrict__ Wc,  // [40][128]
    const float* __restrict__ bc, float* __restrict__ out)
{
    __shared__ float Ws[128][NCLS];
    __shared__ float bs[NCLS];
    int t = threadIdx.x;
    for (int i = t; i < NCLS * 128; i += 256) {
        int c = i >> 7, k = i & 127;
        Ws[k][c] = Wc[i];
    }
    if (t < NCLS) bs[t] = bc[t];
    __syncthreads();

    int lane = t & 63;
    int waveInBlock = t >> 6;
    int sub = lane >> 3;           // node within wave
    int l8 = lane & 7;
    int n = blockIdx.x * 32 + waveInBlock * 8 + sub;
    const float* hn = h + (size_t)n * 128;
    int c0 = l8 * 5;

    float acc[5];
#pragma unroll
    for (int j = 0; j < 5; j++) acc[j] = bs[c0 + j];

    for (int k = 0; k < 128; k += 4) {
        float4 xv = *(const float4*)(hn + k);
#pragma unroll
        for (int j = 0; j < 5; j++) {
            acc[j] = fmaf(xv.x, Ws[k + 0][c0 + j], acc[j]);
            acc[j] = fmaf(xv.y, Ws[k + 1][c0 + j], acc[j]);
            acc[j] = fmaf(xv.z, Ws[k + 2][c0 + j], acc[j]);
            acc[j] = fmaf(xv.w, Ws[k + 3][c0 + j], acc[j]);
        }
    }
    float m = acc[0];
#pragma unroll
    for (int j = 1; j < 5; j++) m = fmaxf(m, acc[j]);
    for (int off = 1; off < 8; off <<= 1) m = fmaxf(m, __shfl_xor(m, off));
    float s = 0.0f;
#pragma unroll
    for (int j = 0; j < 5; j++) s += expf(acc[j] - m);
    for (int off = 1; off < 8; off <<= 1) s += __shfl_xor(s, off);
    float lse = m + logf(s);
    float* on = out + (size_t)n * NCLS + c0;
#pragma unroll
    for (int j = 0; j < 5; j++) on[j] = acc[j] - lse;
}

extern "C" void kernel_launch(void* const* d_in, const int* in_sizes, int n_in,
                              void* d_out, int out_size, void* d_ws, size_t ws_size,
                              hipStream_t stream)
{
    const float* x     = (const float*)d_in[0];
    const int*   ei    = (const int*)d_in[1];   // [2, E] int32
    const float* em    = (const float*)d_in[2];
    // d_in[3] = ptr (uniform partitions; unused)
    const float* w0    = (const float*)d_in[4];
    const float* b0    = (const float*)d_in[5];
    const float* convw = (const float*)d_in[6]; // [3,128,128]
    const float* convb = (const float*)d_in[7]; // [3,128]
    const float* ltw   = (const float*)d_in[8]; // [40,128]
    const float* ltb   = (const float*)d_in[9]; // [40]
    float* out = (float*)d_out;

    char* ws = (char*)d_ws;
    size_t off = 0;
    auto alloc = [&](size_t bytes) -> void* {
        void* p = ws + off;
        off += (bytes + 255) & ~(size_t)255;
        return p;
    };
    float* hA      = (float*)alloc((size_t)NNODES * 128 * 4);
    float* hB      = (float*)alloc((size_t)NNODES * 128 * 4);
    float* Wdyn    = (float*)alloc((size_t)32 * 128 * 128 * 4);
    int*   cnt     = (int*)alloc((size_t)NNODES * 4);
    int*   row_ptr = (int*)alloc((size_t)(NNODES + 1) * 4);
    int*   cursor  = (int*)alloc((size_t)NNODES * 4);
    float* dis     = (float*)alloc((size_t)NNODES * 4);
    int*   csr     = (int*)alloc((size_t)NEDGES * 4);

    const int* esrc = ei;
    const int* edst = ei + NEDGES;

    hipMemsetAsync(cnt, 0, (size_t)NNODES * 4, stream);
    wdyn_kernel<<<2048, 256, 0, stream>>>(w0, em, b0, Wdyn);
    hist_kernel<<<NEDGES / 256, 256, 0, stream>>>(edst, cnt, NEDGES);
    scan_kernel<<<1, 1024, 0, stream>>>(cnt, row_ptr, cursor, dis);
    scatter_kernel<<<NEDGES / 256, 256, 0, stream>>>(esrc, edst, cursor, csr, NEDGES);

    // h0 = x @ Wdyn[g]  (no scaling)
    gemm128<<<NNODES / 128, 256, 0, stream>>>(x, Wdyn, hA, nullptr, 1);

    for (int l = 0; l < 3; l++) {
        // hw_scaled = (h @ W_l) * dis[n]
        gemm128<<<NNODES / 128, 256, 0, stream>>>(hA, convw + (size_t)l * 128 * 128,
                                                  hB, dis, 0);
        // h = relu(dis[n] * (sum_in hw_scaled + self) + b_l)
        aggregate_kernel<<<NNODES * 64 / 256, 256, 0, stream>>>(
            hB, row_ptr, csr, dis, convb + (size_t)l * 128, hA);
    }

    logits_lsm_kernel<<<NNODES / 32, 256, 0, stream>>>(hA, ltw, ltb, out);
}

// Round 2
// 558.980 us; speedup vs baseline: 1.3579x; 1.3579x over previous
//
#include <hip/hip_runtime.h>

#define NNODES 65536
#define NEDGES 1048576
#define HDIM 128
#define NCLS 40

typedef unsigned int uint;

__device__ __forceinline__ float bf_lo(uint v) {
    return __builtin_bit_cast(float, v << 16);
}
__device__ __forceinline__ float bf_hi(uint v) {
    return __builtin_bit_cast(float, v & 0xffff0000u);
}
__device__ __forceinline__ uint pack_bf16x2(float a, float b) {
    uint ua = __builtin_bit_cast(uint, a);
    uint ub = __builtin_bit_cast(uint, b);
    ua += 0x7fff + ((ua >> 16) & 1);   // RNE to bf16
    ub += 0x7fff + ((ub >> 16) & 1);
    return (ua >> 16) | (ub & 0xffff0000u);
}

// ---------------- Wdyn = relu(w0[f]*E_meta[g,h] + b0[f,h]) ----------------
__global__ __launch_bounds__(256) void wdyn_kernel(
    const float* __restrict__ w0, const float* __restrict__ em,
    const float* __restrict__ b0, float* __restrict__ W)
{
    int i = blockIdx.x * 256 + threadIdx.x;   // G*F*H = 524288
    int h = i & 127;
    int f = (i >> 7) & 127;
    int g = i >> 14;
    float v = w0[f] * em[g * 128 + h] + b0[f * 128 + h];
    W[i] = fmaxf(v, 0.0f);
}

// ---------------- degree histogram ----------------
__global__ __launch_bounds__(256) void hist_kernel(
    const int* __restrict__ dst, int* __restrict__ cnt, int nE)
{
    int e = blockIdx.x * 256 + threadIdx.x;
    if (e < nE) atomicAdd(&cnt[dst[e]], 1);
}

// ---------------- single-block scan: row_ptr / cursor / dis ----------------
__global__ __launch_bounds__(1024) void scan_kernel(
    const int* __restrict__ cnt, int* __restrict__ row_ptr,
    int* __restrict__ cursor, float* __restrict__ dis)
{
    __shared__ int ssum[1024];
    int t = threadIdx.x;
    int base = t * 64;
    int s = 0;
    for (int i = 0; i < 64; i++) s += cnt[base + i];
    ssum[t] = s;
    __syncthreads();
    int mine = s;
    for (int off = 1; off < 1024; off <<= 1) {
        int v = (t >= off) ? ssum[t - off] : 0;
        __syncthreads();
        ssum[t] += v;
        __syncthreads();
    }
    int run = ssum[t] - mine;  // exclusive prefix
    for (int i = 0; i < 64; i++) {
        int idx = base + i;
        int c = cnt[idx];
        row_ptr[idx] = run;
        cursor[idx] = run;
        dis[idx] = rsqrtf((float)(c + 1));   // +1 self loop
        run += c;
    }
    if (t == 1023) row_ptr[NNODES] = run;
}

// ---------------- scatter edges into CSR (by dst) ----------------
__global__ __launch_bounds__(256) void scatter_kernel(
    const int* __restrict__ src, const int* __restrict__ dst,
    int* __restrict__ cursor, int* __restrict__ csr, int nE)
{
    int e = blockIdx.x * 256 + threadIdx.x;
    if (e < nE) {
        int pos = atomicAdd(&cursor[dst[e]], 1);
        csr[pos] = src[e];
    }
}

// ---------------- 128x128-tile SGEMM: C[n,:] = A[n,:] @ B (K=128, Ncols=128)
// perGroup: B indexed by node group (row>>11).
// If dis != null: scale row by dis[n] and write PACKED BF16 (Cp as uint[N][64]).
// Else: write fp32 to Cf.
__global__ __launch_bounds__(256) void gemm128(
    const float* __restrict__ A, const float* __restrict__ B,
    float* __restrict__ Cf, uint* __restrict__ Cp,
    const float* __restrict__ dis, int perGroup)
{
    __shared__ float As[8][128];
    __shared__ float Bs[8][128];
    const int t = threadIdx.x;
    const int rowBase = blockIdx.x * 128;
    const float* Bp = perGroup ? (B + ((size_t)(rowBase >> 11) << 14)) : B;
    const int colg = (t & 15) << 3;   // 16 col groups * 8 cols
    const int rowg = (t >> 4) << 3;   // 16 row groups * 8 rows
    float acc[8][8];
#pragma unroll
    for (int i = 0; i < 8; i++)
#pragma unroll
        for (int j = 0; j < 8; j++) acc[i][j] = 0.0f;

    const int lr  = t >> 1;           // 0..127 row for A load
    const int kq  = (t & 1) << 2;     // 0 or 4
    const int kb  = t >> 5;           // 0..7 k-row for B load
    const int col4 = (t & 31) << 2;   // B col

    for (int k0 = 0; k0 < 128; k0 += 8) {
        float4 av = *(const float4*)(A + (size_t)(rowBase + lr) * 128 + k0 + kq);
        float4 bv = *(const float4*)(Bp + (size_t)(k0 + kb) * 128 + col4);
        As[kq + 0][lr] = av.x;
        As[kq + 1][lr] = av.y;
        As[kq + 2][lr] = av.z;
        As[kq + 3][lr] = av.w;
        *(float4*)&Bs[kb][col4] = bv;
        __syncthreads();
#pragma unroll
        for (int kk = 0; kk < 8; kk++) {
            float4 a0 = *(float4*)&As[kk][rowg];
            float4 a1 = *(float4*)&As[kk][rowg + 4];
            float4 b0 = *(float4*)&Bs[kk][colg];
            float4 b1 = *(float4*)&Bs[kk][colg + 4];
            float ar[8] = {a0.x, a0.y, a0.z, a0.w, a1.x, a1.y, a1.z, a1.w};
            float br[8] = {b0.x, b0.y, b0.z, b0.w, b1.x, b1.y, b1.z, b1.w};
#pragma unroll
            for (int i = 0; i < 8; i++)
#pragma unroll
                for (int j = 0; j < 8; j++)
                    acc[i][j] = fmaf(ar[i], br[j], acc[i][j]);
        }
        __syncthreads();
    }
    if (dis) {
#pragma unroll
        for (int i = 0; i < 8; i++) {
            int r = rowBase + rowg + i;
            float scale = dis[r];
            uint4 o;
            o.x = pack_bf16x2(acc[i][0] * scale, acc[i][1] * scale);
            o.y = pack_bf16x2(acc[i][2] * scale, acc[i][3] * scale);
            o.z = pack_bf16x2(acc[i][4] * scale, acc[i][5] * scale);
            o.w = pack_bf16x2(acc[i][6] * scale, acc[i][7] * scale);
            *(uint4*)(Cp + (size_t)r * 64 + (colg >> 1)) = o;
        }
    } else {
#pragma unroll
        for (int i = 0; i < 8; i++) {
            int r = rowBase + rowg + i;
            float4 o0 = make_float4(acc[i][0], acc[i][1], acc[i][2], acc[i][3]);
            float4 o1 = make_float4(acc[i][4], acc[i][5], acc[i][6], acc[i][7]);
            *(float4*)(Cf + (size_t)r * 128 + colg) = o0;
            *(float4*)(Cf + (size_t)r * 128 + colg + 4) = o1;
        }
    }
}

// ---------------- aggregation over packed-bf16 rows ----------------
// out[n] = relu(dis[n]*(sum_src hws[src] + hws[n]) + b); hws pre-scaled by dis[src].
// One wave per node; lane handles features {2*lane, 2*lane+1}; 4-way unrolled
// edge loop for memory-level parallelism.
__global__ __launch_bounds__(256) void aggregate_kernel(
    const uint* __restrict__ hws, const int* __restrict__ row_ptr,
    const int* __restrict__ csr, const float* __restrict__ dis,
    const float* __restrict__ bias, float* __restrict__ outh)
{
    int gid = blockIdx.x * 256 + threadIdx.x;
    int n = gid >> 6;
    int lane = gid & 63;
    int beg = row_ptr[n], end = row_ptr[n + 1];
    uint sv = hws[(size_t)n * 64 + lane];       // self (scaled)
    float ax = bf_lo(sv), ay = bf_hi(sv);
    float bx = 0.0f, by = 0.0f;
    int i = beg;
    for (; i + 4 <= end; i += 4) {
        int s0 = csr[i], s1 = csr[i + 1], s2 = csr[i + 2], s3 = csr[i + 3];
        uint v0 = hws[(size_t)s0 * 64 + lane];
        uint v1 = hws[(size_t)s1 * 64 + lane];
        uint v2 = hws[(size_t)s2 * 64 + lane];
        uint v3 = hws[(size_t)s3 * 64 + lane];
        ax += bf_lo(v0) + bf_lo(v1);
        ay += bf_hi(v0) + bf_hi(v1);
        bx += bf_lo(v2) + bf_lo(v3);
        by += bf_hi(v2) + bf_hi(v3);
    }
    for (; i < end; ++i) {
        uint v = hws[(size_t)csr[i] * 64 + lane];
        ax += bf_lo(v);
        ay += bf_hi(v);
    }
    ax += bx;
    ay += by;
    float d = dis[n];
    float2 b = *(const float2*)(bias + (size_t)(lane * 2));
    float2 o;
    o.x = fmaxf(fmaf(d, ax, b.x), 0.0f);
    o.y = fmaxf(fmaf(d, ay, b.y), 0.0f);
    *(float2*)(outh + (size_t)n * 128 + (size_t)(lane * 2)) = o;
}

// ---------------- fused logits (K=128 -> 40) + log_softmax ----------------
__global__ __launch_bounds__(256) void logits_lsm_kernel(
    const float* __restrict__ h, const float* __restrict__ Wc,  // [40][128]
    const float* __restrict__ bc, float* __restrict__ out)
{
    __shared__ float Ws[128][NCLS];
    __shared__ float bs[NCLS];
    int t = threadIdx.x;
    for (int i = t; i < NCLS * 128; i += 256) {
        int c = i >> 7, k = i & 127;
        Ws[k][c] = Wc[i];
    }
    if (t < NCLS) bs[t] = bc[t];
    __syncthreads();

    int lane = t & 63;
    int waveInBlock = t >> 6;
    int sub = lane >> 3;           // node within wave
    int l8 = lane & 7;
    int n = blockIdx.x * 32 + waveInBlock * 8 + sub;
    const float* hn = h + (size_t)n * 128;
    int c0 = l8 * 5;

    float acc[5];
#pragma unroll
    for (int j = 0; j < 5; j++) acc[j] = bs[c0 + j];

    for (int k = 0; k < 128; k += 4) {
        float4 xv = *(const float4*)(hn + k);
#pragma unroll
        for (int j = 0; j < 5; j++) {
            acc[j] = fmaf(xv.x, Ws[k + 0][c0 + j], acc[j]);
            acc[j] = fmaf(xv.y, Ws[k + 1][c0 + j], acc[j]);
            acc[j] = fmaf(xv.z, Ws[k + 2][c0 + j], acc[j]);
            acc[j] = fmaf(xv.w, Ws[k + 3][c0 + j], acc[j]);
        }
    }
    float m = acc[0];
#pragma unroll
    for (int j = 1; j < 5; j++) m = fmaxf(m, acc[j]);
    for (int off = 1; off < 8; off <<= 1) m = fmaxf(m, __shfl_xor(m, off));
    float s = 0.0f;
#pragma unroll
    for (int j = 0; j < 5; j++) s += expf(acc[j] - m);
    for (int off = 1; off < 8; off <<= 1) s += __shfl_xor(s, off);
    float lse = m + logf(s);
    float* on = out + (size_t)n * NCLS + c0;
#pragma unroll
    for (int j = 0; j < 5; j++) on[j] = acc[j] - lse;
}

extern "C" void kernel_launch(void* const* d_in, const int* in_sizes, int n_in,
                              void* d_out, int out_size, void* d_ws, size_t ws_size,
                              hipStream_t stream)
{
    const float* x     = (const float*)d_in[0];
    const int*   ei    = (const int*)d_in[1];   // [2, E] int32
    const float* em    = (const float*)d_in[2];
    // d_in[3] = ptr (uniform partitions; unused)
    const float* w0    = (const float*)d_in[4];
    const float* b0    = (const float*)d_in[5];
    const float* convw = (const float*)d_in[6]; // [3,128,128]
    const float* convb = (const float*)d_in[7]; // [3,128]
    const float* ltw   = (const float*)d_in[8]; // [40,128]
    const float* ltb   = (const float*)d_in[9]; // [40]
    float* out = (float*)d_out;

    char* ws = (char*)d_ws;
    size_t off = 0;
    auto alloc = [&](size_t bytes) -> void* {
        void* p = ws + off;
        off += (bytes + 255) & ~(size_t)255;
        return p;
    };
    float* hA      = (float*)alloc((size_t)NNODES * 128 * 4);
    uint*  hB      = (uint*)alloc((size_t)NNODES * 64 * 4);   // packed bf16x2
    float* Wdyn    = (float*)alloc((size_t)32 * 128 * 128 * 4);
    int*   cnt     = (int*)alloc((size_t)NNODES * 4);
    int*   row_ptr = (int*)alloc((size_t)(NNODES + 1) * 4);
    int*   cursor  = (int*)alloc((size_t)NNODES * 4);
    float* dis     = (float*)alloc((size_t)NNODES * 4);
    int*   csr     = (int*)alloc((size_t)NEDGES * 4);

    const int* esrc = ei;
    const int* edst = ei + NEDGES;

    hipMemsetAsync(cnt, 0, (size_t)NNODES * 4, stream);
    wdyn_kernel<<<2048, 256, 0, stream>>>(w0, em, b0, Wdyn);
    hist_kernel<<<NEDGES / 256, 256, 0, stream>>>(edst, cnt, NEDGES);
    scan_kernel<<<1, 1024, 0, stream>>>(cnt, row_ptr, cursor, dis);
    scatter_kernel<<<NEDGES / 256, 256, 0, stream>>>(esrc, edst, cursor, csr, NEDGES);

    // h0 = x @ Wdyn[g]  (fp32 out, no scaling)
    gemm128<<<NNODES / 128, 256, 0, stream>>>(x, Wdyn, hA, nullptr, nullptr, 1);

    for (int l = 0; l < 3; l++) {
        // hw_scaled = (h @ W_l) * dis[n]  -> packed bf16
        gemm128<<<NNODES / 128, 256, 0, stream>>>(hA, convw + (size_t)l * 128 * 128,
                                                  nullptr, hB, dis, 0);
        // h = relu(dis[n] * (sum_in hw_scaled + self) + b_l)
        aggregate_kernel<<<NNODES * 64 / 256, 256, 0, stream>>>(
            hB, row_ptr, csr, dis, convb + (size_t)l * 128, hA);
    }

    logits_lsm_kernel<<<NNODES / 32, 256, 0, stream>>>(hA, ltw, ltb, out);
}

// Round 3
// 434.559 us; speedup vs baseline: 1.7467x; 1.2863x over previous
//
#include <hip/hip_runtime.h>

#define NNODES 65536
#define NEDGES 1048576
#define HDIM 128
#define NCLS 40

typedef unsigned int uint;

__device__ __forceinline__ float bf_lo(uint v) {
    return __builtin_bit_cast(float, v << 16);
}
__device__ __forceinline__ float bf_hi(uint v) {
    return __builtin_bit_cast(float, v & 0xffff0000u);
}
__device__ __forceinline__ uint pack_bf16x2(float a, float b) {
    uint ua = __builtin_bit_cast(uint, a);
    uint ub = __builtin_bit_cast(uint, b);
    ua += 0x7fff + ((ua >> 16) & 1);   // RNE to bf16
    ub += 0x7fff + ((ub >> 16) & 1);
    return (ua >> 16) | (ub & 0xffff0000u);
}

// ---------------- Wdyn = relu(w0[f]*E_meta[g,h] + b0[f,h]) ----------------
__global__ __launch_bounds__(256) void wdyn_kernel(
    const float* __restrict__ w0, const float* __restrict__ em,
    const float* __restrict__ b0, float* __restrict__ W)
{
    int i = blockIdx.x * 256 + threadIdx.x;   // G*F*H = 524288
    int h = i & 127;
    int f = (i >> 7) & 127;
    int g = i >> 14;
    float v = w0[f] * em[g * 128 + h] + b0[f * 128 + h];
    W[i] = fmaxf(v, 0.0f);
}

// ======== 2-level binned counting sort of edges by dst ========
// coarse bucket = dst >> 8 (256 buckets, ~4096 edges each)

// Pass A: coarse bucket counts (LDS histogram, sequential read)
__global__ __launch_bounds__(256) void bucket_count(
    const int* __restrict__ dst, int* __restrict__ bcnt)
{
    __shared__ int h[256];
    int t = threadIdx.x;
    h[t] = 0;
    __syncthreads();
    int base = blockIdx.x * 4096;
#pragma unroll
    for (int k = 0; k < 16; k++)
        atomicAdd(&h[((uint)dst[base + k * 256 + t]) >> 8], 1);
    __syncthreads();
    atomicAdd(&bcnt[t], h[t]);
}

// Pass B: exclusive scan of 256 bucket counts -> bucket_base[257]
__global__ __launch_bounds__(256) void bucket_scan(
    const int* __restrict__ bcnt, int* __restrict__ bucket_base)
{
    __shared__ int tmp[256];
    int t = threadIdx.x;
    int v = bcnt[t];
    tmp[t] = v;
    __syncthreads();
    for (int off = 1; off < 256; off <<= 1) {
        int u = (t >= off) ? tmp[t - off] : 0;
        __syncthreads();
        tmp[t] += u;
        __syncthreads();
    }
    bucket_base[t] = tmp[t] - v;   // exclusive
    if (t == 255) bucket_base[256] = NEDGES;
}

// Pass C: bin edges into bucket-contiguous staging (packed (dst<<16)|src)
__global__ __launch_bounds__(256) void bucket_scatter(
    const int* __restrict__ src, const int* __restrict__ dst,
    const int* __restrict__ bucket_base, int* __restrict__ gcursor,
    uint* __restrict__ binned)
{
    __shared__ int lcnt[256];
    __shared__ int lbase[256];
    int t = threadIdx.x;
    int base = blockIdx.x * 4096;
    lcnt[t] = 0;
    __syncthreads();
    uint e[16];
#pragma unroll
    for (int k = 0; k < 16; k++) {
        int i = base + k * 256 + t;
        uint s = (uint)src[i];
        uint d = (uint)dst[i];
        e[k] = (d << 16) | s;
        atomicAdd(&lcnt[d >> 8], 1);
    }
    __syncthreads();
    lbase[t] = bucket_base[t] + atomicAdd(&gcursor[t], lcnt[t]);
    lcnt[t] = 0;
    __syncthreads();
#pragma unroll
    for (int k = 0; k < 16; k++) {
        int b = e[k] >> 24;
        int r = atomicAdd(&lcnt[b], 1);
        binned[lbase[b] + r] = e[k];
    }
}

// Pass D: per-bucket fine CSR build: row_ptr, dis, csr (src ids)
__global__ __launch_bounds__(256) void csr_build(
    const uint* __restrict__ binned, const int* __restrict__ bucket_base,
    int* __restrict__ row_ptr, float* __restrict__ dis, int* __restrict__ csr)
{
    __shared__ int cnt[256];
    __shared__ int tmp[256];
    __shared__ int fb[256];
    int t = threadIdx.x;
    int b = blockIdx.x;
    int e0 = bucket_base[b], e1 = bucket_base[b + 1];
    cnt[t] = 0;
    __syncthreads();
    for (int i = e0 + t; i < e1; i += 256)
        atomicAdd(&cnt[(binned[i] >> 16) & 255], 1);
    __syncthreads();
    int v = cnt[t];
    tmp[t] = v;
    __syncthreads();
    for (int off = 1; off < 256; off <<= 1) {
        int u = (t >= off) ? tmp[t - off] : 0;
        __syncthreads();
        tmp[t] += u;
        __syncthreads();
    }
    fb[t] = tmp[t] - v;   // exclusive fine base
    int node = (b << 8) + t;
    row_ptr[node] = e0 + fb[t];
    dis[node] = rsqrtf((float)(v + 1));   // +1 self loop
    if (node == NNODES - 1) row_ptr[NNODES] = NEDGES;
    cnt[t] = 0;
    __syncthreads();
    for (int i = e0 + t; i < e1; i += 256) {
        uint e = binned[i];
        int d = (e >> 16) & 255;
        int r = atomicAdd(&cnt[d], 1);
        csr[e0 + fb[d] + r] = (int)(e & 0xffffu);
    }
}

// ---------------- 128x128-tile SGEMM: C[n,:] = A[n,:] @ B (K=128, Ncols=128)
// perGroup: B indexed by node group (row>>11).
// If dis != null: scale row by dis[n] and write PACKED BF16 (Cp as uint[N][64]).
// Else: write fp32 to Cf.
__global__ __launch_bounds__(256) void gemm128(
    const float* __restrict__ A, const float* __restrict__ B,
    float* __restrict__ Cf, uint* __restrict__ Cp,
    const float* __restrict__ dis, int perGroup)
{
    __shared__ float As[8][128];
    __shared__ float Bs[8][128];
    const int t = threadIdx.x;
    const int rowBase = blockIdx.x * 128;
    const float* Bp = perGroup ? (B + ((size_t)(rowBase >> 11) << 14)) : B;
    const int colg = (t & 15) << 3;   // 16 col groups * 8 cols
    const int rowg = (t >> 4) << 3;   // 16 row groups * 8 rows
    float acc[8][8];
#pragma unroll
    for (int i = 0; i < 8; i++)
#pragma unroll
        for (int j = 0; j < 8; j++) acc[i][j] = 0.0f;

    const int lr  = t >> 1;           // 0..127 row for A load
    const int kq  = (t & 1) << 2;     // 0 or 4
    const int kb  = t >> 5;           // 0..7 k-row for B load
    const int col4 = (t & 31) << 2;   // B col

    for (int k0 = 0; k0 < 128; k0 += 8) {
        float4 av = *(const float4*)(A + (size_t)(rowBase + lr) * 128 + k0 + kq);
        float4 bv = *(const float4*)(Bp + (size_t)(k0 + kb) * 128 + col4);
        As[kq + 0][lr] = av.x;
        As[kq + 1][lr] = av.y;
        As[kq + 2][lr] = av.z;
        As[kq + 3][lr] = av.w;
        *(float4*)&Bs[kb][col4] = bv;
        __syncthreads();
#pragma unroll
        for (int kk = 0; kk < 8; kk++) {
            float4 a0 = *(float4*)&As[kk][rowg];
            float4 a1 = *(float4*)&As[kk][rowg + 4];
            float4 b0 = *(float4*)&Bs[kk][colg];
            float4 b1 = *(float4*)&Bs[kk][colg + 4];
            float ar[8] = {a0.x, a0.y, a0.z, a0.w, a1.x, a1.y, a1.z, a1.w};
            float br[8] = {b0.x, b0.y, b0.z, b0.w, b1.x, b1.y, b1.z, b1.w};
#pragma unroll
            for (int i = 0; i < 8; i++)
#pragma unroll
                for (int j = 0; j < 8; j++)
                    acc[i][j] = fmaf(ar[i], br[j], acc[i][j]);
        }
        __syncthreads();
    }
    if (dis) {
#pragma unroll
        for (int i = 0; i < 8; i++) {
            int r = rowBase + rowg + i;
            float scale = dis[r];
            uint4 o;
            o.x = pack_bf16x2(acc[i][0] * scale, acc[i][1] * scale);
            o.y = pack_bf16x2(acc[i][2] * scale, acc[i][3] * scale);
            o.z = pack_bf16x2(acc[i][4] * scale, acc[i][5] * scale);
            o.w = pack_bf16x2(acc[i][6] * scale, acc[i][7] * scale);
            *(uint4*)(Cp + (size_t)r * 64 + (colg >> 1)) = o;
        }
    } else {
#pragma unroll
        for (int i = 0; i < 8; i++) {
            int r = rowBase + rowg + i;
            float4 o0 = make_float4(acc[i][0], acc[i][1], acc[i][2], acc[i][3]);
            float4 o1 = make_float4(acc[i][4], acc[i][5], acc[i][6], acc[i][7]);
            *(float4*)(Cf + (size_t)r * 128 + colg) = o0;
            *(float4*)(Cf + (size_t)r * 128 + colg + 4) = o1;
        }
    }
}

// ---------------- aggregation over packed-bf16 rows ----------------
__global__ __launch_bounds__(256) void aggregate_kernel(
    const uint* __restrict__ hws, const int* __restrict__ row_ptr,
    const int* __restrict__ csr, const float* __restrict__ dis,
    const float* __restrict__ bias, float* __restrict__ outh)
{
    int gid = blockIdx.x * 256 + threadIdx.x;
    int n = gid >> 6;
    int lane = gid & 63;
    int beg = row_ptr[n], end = row_ptr[n + 1];
    uint sv = hws[(size_t)n * 64 + lane];       // self (scaled)
    float ax = bf_lo(sv), ay = bf_hi(sv);
    float bx = 0.0f, by = 0.0f;
    int i = beg;
    for (; i + 4 <= end; i += 4) {
        int s0 = csr[i], s1 = csr[i + 1], s2 = csr[i + 2], s3 = csr[i + 3];
        uint v0 = hws[(size_t)s0 * 64 + lane];
        uint v1 = hws[(size_t)s1 * 64 + lane];
        uint v2 = hws[(size_t)s2 * 64 + lane];
        uint v3 = hws[(size_t)s3 * 64 + lane];
        ax += bf_lo(v0) + bf_lo(v1);
        ay += bf_hi(v0) + bf_hi(v1);
        bx += bf_lo(v2) + bf_lo(v3);
        by += bf_hi(v2) + bf_hi(v3);
    }
    for (; i < end; ++i) {
        uint v = hws[(size_t)csr[i] * 64 + lane];
        ax += bf_lo(v);
        ay += bf_hi(v);
    }
    ax += bx;
    ay += by;
    float d = dis[n];
    float2 b = *(const float2*)(bias + (size_t)(lane * 2));
    float2 o;
    o.x = fmaxf(fmaf(d, ax, b.x), 0.0f);
    o.y = fmaxf(fmaf(d, ay, b.y), 0.0f);
    *(float2*)(outh + (size_t)n * 128 + (size_t)(lane * 2)) = o;
}

// ---------------- fused logits (K=128 -> 40) + log_softmax ----------------
__global__ __launch_bounds__(256) void logits_lsm_kernel(
    const float* __restrict__ h, const float* __restrict__ Wc,  // [40][128]
    const float* __restrict__ bc, float* __restrict__ out)
{
    __shared__ float Ws[128][NCLS];
    __shared__ float bs[NCLS];
    int t = threadIdx.x;
    for (int i = t; i < NCLS * 128; i += 256) {
        int c = i >> 7, k = i & 127;
        Ws[k][c] = Wc[i];
    }
    if (t < NCLS) bs[t] = bc[t];
    __syncthreads();

    int lane = t & 63;
    int waveInBlock = t >> 6;
    int sub = lane >> 3;           // node within wave
    int l8 = lane & 7;
    int n = blockIdx.x * 32 + waveInBlock * 8 + sub;
    const float* hn = h + (size_t)n * 128;
    int c0 = l8 * 5;

    float acc[5];
#pragma unroll
    for (int j = 0; j < 5; j++) acc[j] = bs[c0 + j];

    for (int k = 0; k < 128; k += 4) {
        float4 xv = *(const float4*)(hn + k);
#pragma unroll
        for (int j = 0; j < 5; j++) {
            acc[j] = fmaf(xv.x, Ws[k + 0][c0 + j], acc[j]);
            acc[j] = fmaf(xv.y, Ws[k + 1][c0 + j], acc[j]);
            acc[j] = fmaf(xv.z, Ws[k + 2][c0 + j], acc[j]);
            acc[j] = fmaf(xv.w, Ws[k + 3][c0 + j], acc[j]);
        }
    }
    float m = acc[0];
#pragma unroll
    for (int j = 1; j < 5; j++) m = fmaxf(m, acc[j]);
    for (int off = 1; off < 8; off <<= 1) m = fmaxf(m, __shfl_xor(m, off));
    float s = 0.0f;
#pragma unroll
    for (int j = 0; j < 5; j++) s += expf(acc[j] - m);
    for (int off = 1; off < 8; off <<= 1) s += __shfl_xor(s, off);
    float lse = m + logf(s);
    float* on = out + (size_t)n * NCLS + c0;
#pragma unroll
    for (int j = 0; j < 5; j++) on[j] = acc[j] - lse;
}

extern "C" void kernel_launch(void* const* d_in, const int* in_sizes, int n_in,
                              void* d_out, int out_size, void* d_ws, size_t ws_size,
                              hipStream_t stream)
{
    const float* x     = (const float*)d_in[0];
    const int*   ei    = (const int*)d_in[1];   // [2, E] int32
    const float* em    = (const float*)d_in[2];
    // d_in[3] = ptr (uniform partitions; unused)
    const float* w0    = (const float*)d_in[4];
    const float* b0    = (const float*)d_in[5];
    const float* convw = (const float*)d_in[6]; // [3,128,128]
    const float* convb = (const float*)d_in[7]; // [3,128]
    const float* ltw   = (const float*)d_in[8]; // [40,128]
    const float* ltb   = (const float*)d_in[9]; // [40]
    float* out = (float*)d_out;

    char* ws = (char*)d_ws;
    size_t off = 0;
    auto alloc = [&](size_t bytes) -> void* {
        void* p = ws + off;
        off += (bytes + 255) & ~(size_t)255;
        return p;
    };
    float* hA          = (float*)alloc((size_t)NNODES * 128 * 4);
    uint*  hB          = (uint*)alloc((size_t)NNODES * 64 * 4);   // packed bf16x2
    float* Wdyn        = (float*)alloc((size_t)32 * 128 * 128 * 4);
    int*   bcnt        = (int*)alloc(256 * 4);
    int*   bucket_base = (int*)alloc(257 * 4);
    int*   gcursor     = (int*)alloc(256 * 4);
    uint*  binned      = (uint*)alloc((size_t)NEDGES * 4);
    int*   row_ptr     = (int*)alloc((size_t)(NNODES + 1) * 4);
    float* dis         = (float*)alloc((size_t)NNODES * 4);
    int*   csr         = (int*)alloc((size_t)NEDGES * 4);

    const int* esrc = ei;
    const int* edst = ei + NEDGES;

    hipMemsetAsync(bcnt, 0, 256 * 4, stream);
    hipMemsetAsync(gcursor, 0, 256 * 4, stream);
    wdyn_kernel<<<2048, 256, 0, stream>>>(w0, em, b0, Wdyn);
    bucket_count<<<NEDGES / 4096, 256, 0, stream>>>(edst, bcnt);
    bucket_scan<<<1, 256, 0, stream>>>(bcnt, bucket_base);
    bucket_scatter<<<NEDGES / 4096, 256, 0, stream>>>(esrc, edst, bucket_base,
                                                      gcursor, binned);
    csr_build<<<256, 256, 0, stream>>>(binned, bucket_base, row_ptr, dis, csr);

    // h0 = x @ Wdyn[g]  (fp32 out, no scaling)
    gemm128<<<NNODES / 128, 256, 0, stream>>>(x, Wdyn, hA, nullptr, nullptr, 1);

    for (int l = 0; l < 3; l++) {
        // hw_scaled = (h @ W_l) * dis[n]  -> packed bf16
        gemm128<<<NNODES / 128, 256, 0, stream>>>(hA, convw + (size_t)l * 128 * 128,
                                                  nullptr, hB, dis, 0);
        // h = relu(dis[n] * (sum_in hw_scaled + self) + b_l)
        aggregate_kernel<<<NNODES * 64 / 256, 256, 0, stream>>>(
            hB, row_ptr, csr, dis, convb + (size_t)l * 128, hA);
    }

    logits_lsm_kernel<<<NNODES / 32, 256, 0, stream>>>(hA, ltw, ltb, out);
}

// Round 4
// 396.087 us; speedup vs baseline: 1.9163x; 1.0971x over previous
//
#include <hip/hip_runtime.h>

#define NNODES 65536
#define NEDGES 1048576
#define HDIM 128
#define NCLS 40

typedef unsigned int uint;
typedef __attribute__((ext_vector_type(8))) short bf16x8;
typedef __attribute__((ext_vector_type(4))) float f32x4;

__device__ __forceinline__ float bf_lo(uint v) {
    return __builtin_bit_cast(float, v << 16);
}
__device__ __forceinline__ float bf_hi(uint v) {
    return __builtin_bit_cast(float, v & 0xffff0000u);
}
__device__ __forceinline__ uint pack_bf16x2(float a, float b) {
    uint ua = __builtin_bit_cast(uint, a);
    uint ub = __builtin_bit_cast(uint, b);
    ua += 0x7fff + ((ua >> 16) & 1);   // RNE to bf16
    ub += 0x7fff + ((ub >> 16) & 1);
    return (ua >> 16) | (ub & 0xffff0000u);
}

// ---------------- WdynT[g][h][fpair] = relu(w0[f]*E_meta[g,h] + b0[f,h]) (bf16 packed)
__global__ __launch_bounds__(256) void wdyn_kernel(
    const float* __restrict__ w0, const float* __restrict__ em,
    const float* __restrict__ b0, uint* __restrict__ WT)
{
    int i = blockIdx.x * 256 + threadIdx.x;   // G*H*64 = 262144
    int fp = i & 63;
    int h = (i >> 6) & 127;
    int g = i >> 13;
    int f0 = fp * 2;
    float e = em[g * 128 + h];
    float v0 = fmaxf(w0[f0] * e + b0[f0 * 128 + h], 0.0f);
    float v1 = fmaxf(w0[f0 + 1] * e + b0[(f0 + 1) * 128 + h], 0.0f);
    WT[i] = pack_bf16x2(v0, v1);
}

// ---------------- convwT[l][o][ipair] = convw[l][i][o] (bf16 packed transpose)
__global__ __launch_bounds__(256) void convT_kernel(
    const float* __restrict__ cw, uint* __restrict__ WT)
{
    int idx = blockIdx.x * 256 + threadIdx.x;  // 3*128*64 = 24576
    int ip = idx & 63;
    int o = (idx >> 6) & 127;
    int l = idx >> 13;
    int i0 = ip * 2;
    float v0 = cw[l * 16384 + i0 * 128 + o];
    float v1 = cw[l * 16384 + (i0 + 1) * 128 + o];
    WT[idx] = pack_bf16x2(v0, v1);
}

// ======== 2-level binned counting sort of edges by dst ========
__global__ __launch_bounds__(256) void bucket_count(
    const int* __restrict__ dst, int* __restrict__ bcnt)
{
    __shared__ int h[256];
    int t = threadIdx.x;
    h[t] = 0;
    __syncthreads();
    int base = blockIdx.x * 4096;
#pragma unroll
    for (int k = 0; k < 16; k++)
        atomicAdd(&h[((uint)dst[base + k * 256 + t]) >> 8], 1);
    __syncthreads();
    atomicAdd(&bcnt[t], h[t]);
}

__global__ __launch_bounds__(256) void bucket_scan(
    const int* __restrict__ bcnt, int* __restrict__ bucket_base)
{
    __shared__ int tmp[256];
    int t = threadIdx.x;
    int v = bcnt[t];
    tmp[t] = v;
    __syncthreads();
    for (int off = 1; off < 256; off <<= 1) {
        int u = (t >= off) ? tmp[t - off] : 0;
        __syncthreads();
        tmp[t] += u;
        __syncthreads();
    }
    bucket_base[t] = tmp[t] - v;   // exclusive
    if (t == 255) bucket_base[256] = NEDGES;
}

__global__ __launch_bounds__(256) void bucket_scatter(
    const int* __restrict__ src, const int* __restrict__ dst,
    const int* __restrict__ bucket_base, int* __restrict__ gcursor,
    uint* __restrict__ binned)
{
    __shared__ int lcnt[256];
    __shared__ int lbase[256];
    int t = threadIdx.x;
    int base = blockIdx.x * 4096;
    lcnt[t] = 0;
    __syncthreads();
    uint e[16];
#pragma unroll
    for (int k = 0; k < 16; k++) {
        int i = base + k * 256 + t;
        uint s = (uint)src[i];
        uint d = (uint)dst[i];
        e[k] = (d << 16) | s;
        atomicAdd(&lcnt[d >> 8], 1);
    }
    __syncthreads();
    lbase[t] = bucket_base[t] + atomicAdd(&gcursor[t], lcnt[t]);
    lcnt[t] = 0;
    __syncthreads();
#pragma unroll
    for (int k = 0; k < 16; k++) {
        int b = e[k] >> 24;
        int r = atomicAdd(&lcnt[b], 1);
        binned[lbase[b] + r] = e[k];
    }
}

__global__ __launch_bounds__(256) void csr_build(
    const uint* __restrict__ binned, const int* __restrict__ bucket_base,
    int* __restrict__ row_ptr, float* __restrict__ dis, int* __restrict__ csr)
{
    __shared__ int cnt[256];
    __shared__ int tmp[256];
    __shared__ int fb[256];
    int t = threadIdx.x;
    int b = blockIdx.x;
    int e0 = bucket_base[b], e1 = bucket_base[b + 1];
    cnt[t] = 0;
    __syncthreads();
    for (int i = e0 + t; i < e1; i += 256)
        atomicAdd(&cnt[(binned[i] >> 16) & 255], 1);
    __syncthreads();
    int v = cnt[t];
    tmp[t] = v;
    __syncthreads();
    for (int off = 1; off < 256; off <<= 1) {
        int u = (t >= off) ? tmp[t - off] : 0;
        __syncthreads();
        tmp[t] += u;
        __syncthreads();
    }
    fb[t] = tmp[t] - v;   // exclusive fine base
    int node = (b << 8) + t;
    row_ptr[node] = e0 + fb[t];
    dis[node] = rsqrtf((float)(v + 1));   // +1 self loop
    if (node == NNODES - 1) row_ptr[NNODES] = NEDGES;
    cnt[t] = 0;
    __syncthreads();
    for (int i = e0 + t; i < e1; i += 256) {
        uint e = binned[i];
        int d = (e >> 16) & 255;
        int r = atomicAdd(&cnt[d], 1);
        csr[e0 + fb[d] + r] = (int)(e & 0xffffu);
    }
}

// ---------------- MFMA GEMM: C[m,:] = A[m,:128] @ B (K=128, N=128) ----------------
// A fp32 [M][128], converted to bf16 fragments in-register.
// BT: packed bf16 pairs [128 cols][64 kpairs] (= B^T), perGroup -> per 2048-row group.
// dis == null : write fp32 Cf[M][128]
// dis != null : write packed bf16 Cp[M][64], row-scaled by dis.
// Verified layouts (learn_hip m89/m91): A[m=lane&15][k=quad*8+j],
// B[k=quad*8+j][n=lane&15], C/D col=lane&15 row=quad*4+reg.
__global__ __launch_bounds__(256) void gemm_mfma(
    const float* __restrict__ A, const uint* __restrict__ BT,
    float* __restrict__ Cf, uint* __restrict__ Cp,
    const float* __restrict__ dis, int perGroup)
{
    const int t = threadIdx.x;
    const int wave = t >> 6;
    const int lane = t & 63;
    const int q = lane >> 4;
    const int l16 = lane & 15;
    const int rowBase = blockIdx.x * 128;
    const uint* Bp = perGroup ? BT + ((size_t)(rowBase >> 11) << 13) : BT;

    f32x4 acc[2][8];
#pragma unroll
    for (int r = 0; r < 2; r++)
#pragma unroll
        for (int c = 0; c < 8; c++) {
            acc[r][c][0] = 0.f; acc[r][c][1] = 0.f;
            acc[r][c][2] = 0.f; acc[r][c][3] = 0.f;
        }

    const int mBase = rowBase + wave * 32 + l16;

#pragma unroll
    for (int k0 = 0; k0 < 128; k0 += 32) {
        const int kf = k0 + q * 8;
        bf16x8 afrag[2];
#pragma unroll
        for (int r = 0; r < 2; r++) {
            const float* ap = A + (size_t)(mBase + r * 16) * 128 + kf;
            float4 a0 = *(const float4*)ap;
            float4 a1 = *(const float4*)(ap + 4);
            uint4 u;
            u.x = pack_bf16x2(a0.x, a0.y);
            u.y = pack_bf16x2(a0.z, a0.w);
            u.z = pack_bf16x2(a1.x, a1.y);
            u.w = pack_bf16x2(a1.z, a1.w);
            afrag[r] = __builtin_bit_cast(bf16x8, u);
        }
        bf16x8 bfrag[8];
#pragma unroll
        for (int c = 0; c < 8; c++) {
            const uint* bp = Bp + (size_t)(c * 16 + l16) * 64 + (kf >> 1);
            uint4 u = *(const uint4*)bp;
            bfrag[c] = __builtin_bit_cast(bf16x8, u);
        }
#pragma unroll
        for (int r = 0; r < 2; r++)
#pragma unroll
            for (int c = 0; c < 8; c++)
                acc[r][c] = __builtin_amdgcn_mfma_f32_16x16x32_bf16(
                    afrag[r], bfrag[c], acc[r][c], 0, 0, 0);
    }

    if (dis) {
#pragma unroll
        for (int r = 0; r < 2; r++) {
            int row0 = rowBase + wave * 32 + r * 16 + q * 4;
#pragma unroll
            for (int i = 0; i < 4; i++) {
                int row = row0 + i;
                float s = dis[row];
#pragma unroll
                for (int c = 0; c < 8; c++) {
                    float v = acc[r][c][i] * s;
                    float w = __shfl_xor(v, 1);
                    uint p = (lane & 1) ? pack_bf16x2(w, v) : pack_bf16x2(v, w);
                    if (!(lane & 1))
                        Cp[(size_t)row * 64 + c * 8 + (l16 >> 1)] = p;
                }
            }
        }
    } else {
#pragma unroll
        for (int r = 0; r < 2; r++) {
            int row0 = rowBase + wave * 32 + r * 16 + q * 4;
#pragma unroll
            for (int i = 0; i < 4; i++) {
                float* crow = Cf + (size_t)(row0 + i) * 128 + l16;
#pragma unroll
                for (int c = 0; c < 8; c++) crow[c * 16] = acc[r][c][i];
            }
        }
    }
}

// ---------------- aggregation over packed-bf16 rows ----------------
__global__ __launch_bounds__(256) void aggregate_kernel(
    const uint* __restrict__ hws, const int* __restrict__ row_ptr,
    const int* __restrict__ csr, const float* __restrict__ dis,
    const float* __restrict__ bias, float* __restrict__ outh)
{
    int gid = blockIdx.x * 256 + threadIdx.x;
    int n = gid >> 6;
    int lane = gid & 63;
    int beg = row_ptr[n], end = row_ptr[n + 1];
    uint sv = hws[(size_t)n * 64 + lane];       // self (scaled)
    float ax = bf_lo(sv), ay = bf_hi(sv);
    float bx = 0.0f, by = 0.0f;
    int i = beg;
    for (; i + 4 <= end; i += 4) {
        int s0 = csr[i], s1 = csr[i + 1], s2 = csr[i + 2], s3 = csr[i + 3];
        uint v0 = hws[(size_t)s0 * 64 + lane];
        uint v1 = hws[(size_t)s1 * 64 + lane];
        uint v2 = hws[(size_t)s2 * 64 + lane];
        uint v3 = hws[(size_t)s3 * 64 + lane];
        ax += bf_lo(v0) + bf_lo(v1);
        ay += bf_hi(v0) + bf_hi(v1);
        bx += bf_lo(v2) + bf_lo(v3);
        by += bf_hi(v2) + bf_hi(v3);
    }
    for (; i < end; ++i) {
        uint v = hws[(size_t)csr[i] * 64 + lane];
        ax += bf_lo(v);
        ay += bf_hi(v);
    }
    ax += bx;
    ay += by;
    float d = dis[n];
    float2 b = *(const float2*)(bias + (size_t)(lane * 2));
    float2 o;
    o.x = fmaxf(fmaf(d, ax, b.x), 0.0f);
    o.y = fmaxf(fmaf(d, ay, b.y), 0.0f);
    *(float2*)(outh + (size_t)n * 128 + (size_t)(lane * 2)) = o;
}

// ---------------- fused logits (K=128 -> 40) + log_softmax ----------------
__global__ __launch_bounds__(256) void logits_lsm_kernel(
    const float* __restrict__ h, const float* __restrict__ Wc,  // [40][128]
    const float* __restrict__ bc, float* __restrict__ out)
{
    __shared__ float Ws[128][NCLS];
    __shared__ float bs[NCLS];
    int t = threadIdx.x;
    for (int i = t; i < NCLS * 128; i += 256) {
        int c = i >> 7, k = i & 127;
        Ws[k][c] = Wc[i];
    }
    if (t < NCLS) bs[t] = bc[t];
    __syncthreads();

    int lane = t & 63;
    int waveInBlock = t >> 6;
    int sub = lane >> 3;           // node within wave
    int l8 = lane & 7;
    int n = blockIdx.x * 32 + waveInBlock * 8 + sub;
    const float* hn = h + (size_t)n * 128;
    int c0 = l8 * 5;

    float acc[5];
#pragma unroll
    for (int j = 0; j < 5; j++) acc[j] = bs[c0 + j];

    for (int k = 0; k < 128; k += 4) {
        float4 xv = *(const float4*)(hn + k);
#pragma unroll
        for (int j = 0; j < 5; j++) {
            acc[j] = fmaf(xv.x, Ws[k + 0][c0 + j], acc[j]);
            acc[j] = fmaf(xv.y, Ws[k + 1][c0 + j], acc[j]);
            acc[j] = fmaf(xv.z, Ws[k + 2][c0 + j], acc[j]);
            acc[j] = fmaf(xv.w, Ws[k + 3][c0 + j], acc[j]);
        }
    }
    float m = acc[0];
#pragma unroll
    for (int j = 1; j < 5; j++) m = fmaxf(m, acc[j]);
    for (int off = 1; off < 8; off <<= 1) m = fmaxf(m, __shfl_xor(m, off));
    float s = 0.0f;
#pragma unroll
    for (int j = 0; j < 5; j++) s += expf(acc[j] - m);
    for (int off = 1; off < 8; off <<= 1) s += __shfl_xor(s, off);
    float lse = m + logf(s);
    float* on = out + (size_t)n * NCLS + c0;
#pragma unroll
    for (int j = 0; j < 5; j++) on[j] = acc[j] - lse;
}

extern "C" void kernel_launch(void* const* d_in, const int* in_sizes, int n_in,
                              void* d_out, int out_size, void* d_ws, size_t ws_size,
                              hipStream_t stream)
{
    const float* x     = (const float*)d_in[0];
    const int*   ei    = (const int*)d_in[1];   // [2, E] int32
    const float* em    = (const float*)d_in[2];
    // d_in[3] = ptr (uniform partitions; unused)
    const float* w0    = (const float*)d_in[4];
    const float* b0    = (const float*)d_in[5];
    const float* convw = (const float*)d_in[6]; // [3,128,128]
    const float* convb = (const float*)d_in[7]; // [3,128]
    const float* ltw   = (const float*)d_in[8]; // [40,128]
    const float* ltb   = (const float*)d_in[9]; // [40]
    float* out = (float*)d_out;

    char* ws = (char*)d_ws;
    size_t off = 0;
    auto alloc = [&](size_t bytes) -> void* {
        void* p = ws + off;
        off += (bytes + 255) & ~(size_t)255;
        return p;
    };
    float* hA          = (float*)alloc((size_t)NNODES * 128 * 4);
    uint*  hB          = (uint*)alloc((size_t)NNODES * 64 * 4);   // packed bf16x2
    uint*  WdynT       = (uint*)alloc((size_t)32 * 128 * 64 * 4);
    uint*  convwT      = (uint*)alloc((size_t)3 * 128 * 64 * 4);
    int*   bcnt        = (int*)alloc(256 * 4);
    int*   bucket_base = (int*)alloc(257 * 4);
    int*   gcursor     = (int*)alloc(256 * 4);
    uint*  binned      = (uint*)alloc((size_t)NEDGES * 4);
    int*   row_ptr     = (int*)alloc((size_t)(NNODES + 1) * 4);
    float* dis         = (float*)alloc((size_t)NNODES * 4);
    int*   csr         = (int*)alloc((size_t)NEDGES * 4);

    const int* esrc = ei;
    const int* edst = ei + NEDGES;

    hipMemsetAsync(bcnt, 0, 256 * 4, stream);
    hipMemsetAsync(gcursor, 0, 256 * 4, stream);
    wdyn_kernel<<<1024, 256, 0, stream>>>(w0, em, b0, WdynT);
    convT_kernel<<<96, 256, 0, stream>>>(convw, convwT);
    bucket_count<<<NEDGES / 4096, 256, 0, stream>>>(edst, bcnt);
    bucket_scan<<<1, 256, 0, stream>>>(bcnt, bucket_base);
    bucket_scatter<<<NEDGES / 4096, 256, 0, stream>>>(esrc, edst, bucket_base,
                                                      gcursor, binned);
    csr_build<<<256, 256, 0, stream>>>(binned, bucket_base, row_ptr, dis, csr);

    // h0 = x @ Wdyn[g]  (fp32 out)
    gemm_mfma<<<NNODES / 128, 256, 0, stream>>>(x, WdynT, hA, nullptr, nullptr, 1);

    for (int l = 0; l < 3; l++) {
        // hw_scaled = (h @ W_l) * dis[n]  -> packed bf16
        gemm_mfma<<<NNODES / 128, 256, 0, stream>>>(hA, convwT + (size_t)l * 8192,
                                                    nullptr, hB, dis, 0);
        // h = relu(dis[n] * (sum_in hw_scaled + self) + b_l)
        aggregate_kernel<<<NNODES * 64 / 256, 256, 0, stream>>>(
            hB, row_ptr, csr, dis, convb + (size_t)l * 128, hA);
    }

    logits_lsm_kernel<<<NNODES / 32, 256, 0, stream>>>(hA, ltw, ltb, out);
}